// Round 13
// baseline (1076.273 us; speedup 1.0000x reference)
//
#include <hip/hip_runtime.h>

#define DIM 128
#define EPB 8192              // edges per pass-A block
#define BINSH 8               // coarse bin = 256 consecutive node ids
#define BINN 256
#define SORT_CAP 9456         // LDS staging (bin mean ~8184, +14 sigma)

typedef unsigned int uint32;
typedef __attribute__((ext_vector_type(8))) short short8;
typedef __attribute__((ext_vector_type(4))) float f32x4;

__device__ __forceinline__ uint32 bf16_rtne(float f) {
  uint32 u = __float_as_uint(f);
  return (u + 0x7FFFu + ((u >> 16) & 1u)) >> 16;
}
__device__ __forceinline__ float bf16_to_f(uint32 h) { return __uint_as_float(h << 16); }
__device__ __forceinline__ void unpack2(uint32 u, float& x, float& y) {
  x = __uint_as_float(u << 16);
  y = __uint_as_float(u & 0xFFFF0000u);
}

// ---------------- CSR build pass A: in-LDS counting sort by coarse bin ----------------

__launch_bounds__(256)
__global__ void csr_sort_kernel(const int* __restrict__ src, const int* __restrict__ dst,
                                int E, int nb1, uint32* __restrict__ tmp,
                                int* __restrict__ dir) {
  __shared__ uint32 sorted[EPB];       // 32 KB
  __shared__ int lcnt[512];
  __shared__ int lbase[512];
  __shared__ int ps[256];
  int t = threadIdx.x;
  int base = blockIdx.x * EPB;

  lcnt[t] = 0;
  lcnt[t + 256] = 0;
  __syncthreads();

  uint32 val[32];
  uint32 br[32];   // (bin<<13) | rank
#pragma unroll
  for (int i = 0; i < 32; ++i) {
    int e = base + i * 256 + t;
    if (e < E) {
      int d = __builtin_nontemporal_load(dst + e);
      int s = __builtin_nontemporal_load(src + e);
      int bin = d >> BINSH;
      val[i] = ((uint32)s << BINSH) | (uint32)(d & (BINN - 1));
      int rank = atomicAdd(&lcnt[bin], 1);
      br[i] = ((uint32)bin << 13) | (uint32)rank;
    } else {
      br[i] = 0xFFFFFFFFu;
    }
  }
  __syncthreads();

  {
    int a0 = lcnt[2 * t], a1 = lcnt[2 * t + 1];
    int psum = a0 + a1;
    ps[t] = psum;
    __syncthreads();
    for (int off = 1; off < 256; off <<= 1) {
      int x = (t >= off) ? ps[t - off] : 0;
      __syncthreads();
      ps[t] += x;
      __syncthreads();
    }
    int ebase = ps[t] - psum;
    lbase[2 * t] = ebase;
    lbase[2 * t + 1] = ebase + a0;
  }
  __syncthreads();

#pragma unroll
  for (int i = 0; i < 32; ++i) {
    if (br[i] != 0xFFFFFFFFu) {
      int bin = br[i] >> 13;
      int rank = br[i] & 0x1FFF;
      sorted[lbase[bin] + rank] = val[i];
    }
  }
  __syncthreads();

  int cnt = min(EPB, E - base);
#pragma unroll
  for (int i = 0; i < 32; ++i) {
    int idx = i * 256 + t;
    if (idx < cnt) tmp[base + idx] = sorted[idx];
  }
  for (int b = t; b <= nb1; b += 256) {
    dir[blockIdx.x * (nb1 + 1) + b] = lbase[b];
  }
}

// ---------------- CSR build pass B: one block per bin, single global read of tmp ----------------

__launch_bounds__(256)
__global__ void csr_build_kernel(const uint32* __restrict__ tmp, const int* __restrict__ dir,
                                 int nA, int nb1, int N, int binCap,
                                 int* __restrict__ row_beg, int* __restrict__ row_end,
                                 int* __restrict__ cols, float* __restrict__ dinv) {
  __shared__ uint32 stage[SORT_CAP];   // 37.8 KB
  __shared__ int rbeg[512];
  __shared__ int rend[512];
  __shared__ int rpos[512];
  __shared__ int deg[BINN];
  __shared__ int cur[BINN];
  __shared__ int ps[256];
  int j = blockIdx.x;
  int t = threadIdx.x;
  int node0 = j << BINSH;
  int colsBase = j * binCap;

  if (t < BINN) deg[t] = 0;
  for (int i = t; i < nA; i += 256) {
    rbeg[i] = dir[i * (nb1 + 1) + j];
    rend[i] = dir[i * (nb1 + 1) + j + 1];
  }
  __syncthreads();

  // prefix over run lengths -> rpos (stage offsets), cnt
  {
    int i0 = 2 * t, i1 = 2 * t + 1;
    int l0 = (i0 < nA) ? (rend[i0] - rbeg[i0]) : 0;
    int l1 = (i1 < nA) ? (rend[i1] - rbeg[i1]) : 0;
    int psum = l0 + l1;
    ps[t] = psum;
    __syncthreads();
    for (int off = 1; off < 256; off <<= 1) {
      int x = (t >= off) ? ps[t - off] : 0;
      __syncthreads();
      ps[t] += x;
      __syncthreads();
    }
    int ebase = ps[t] - psum;
    if (i0 < nA) rpos[i0] = ebase;
    if (i1 < nA) rpos[i1] = ebase + l0;
  }
  __syncthreads();
  int cnt = ps[255];
  __syncthreads();

  if (cnt <= SORT_CAP) {
    // stage all runs into LDS (single global read of tmp)
    for (int i = 0; i < nA; ++i) {
      int b = rbeg[i];
      int len = rend[i] - b;
      for (int q = t; q < len; q += 256) stage[rpos[i] + q] = tmp[(size_t)i * EPB + b + q];
    }
    __syncthreads();
    // histogram
    for (int p = t; p < cnt; p += 256) atomicAdd(&deg[stage[p] & (BINN - 1)], 1);
    __syncthreads();
    // scan over deg
    int dv = deg[t];
    ps[t] = dv;
    __syncthreads();
    for (int off = 1; off < 256; off <<= 1) {
      int x = (t >= off) ? ps[t - off] : 0;
      __syncthreads();
      ps[t] += x;
      __syncthreads();
    }
    int ebase = ps[t] - dv;
    cur[t] = ebase;
    int node = node0 + t;
    if (node < N) {
      row_beg[node] = colsBase + ebase;
      row_end[node] = colsBase + ebase + dv;
      dinv[node] = rsqrtf((float)dv + 1.0f);
    }
    __syncthreads();
    // scatter from LDS into this bin's cols window
    for (int p = t; p < cnt; p += 256) {
      uint32 v = stage[p];
      int q = atomicAdd(&cur[v & (BINN - 1)], 1);
      cols[colsBase + q] = (int)(v >> BINSH);
    }
  } else {
    // fallback: two-pass global (should not happen for uniform-random edges)
    for (int i = t; i < nA; i += 256) {
      int b = rbeg[i], en = rend[i];
      for (int q = b; q < en; ++q) {
        atomicAdd(&deg[tmp[(size_t)i * EPB + q] & (BINN - 1)], 1);
      }
    }
    __syncthreads();
    int dv = deg[t];
    ps[t] = dv;
    __syncthreads();
    for (int off = 1; off < 256; off <<= 1) {
      int x = (t >= off) ? ps[t - off] : 0;
      __syncthreads();
      ps[t] += x;
      __syncthreads();
    }
    int ebase = ps[t] - dv;
    cur[t] = ebase;
    int node = node0 + t;
    if (node < N) {
      row_beg[node] = colsBase + ebase;
      row_end[node] = colsBase + ebase + dv;
      dinv[node] = rsqrtf((float)dv + 1.0f);
    }
    __syncthreads();
    for (int i = t; i < nA; i += 256) {
      int b = rbeg[i], en = rend[i];
      for (int q = b; q < en; ++q) {
        uint32 v = tmp[(size_t)i * EPB + q];
        int p = atomicAdd(&cur[v & (BINN - 1)], 1);
        cols[colsBase + p] = (int)(v >> BINSH);
      }
    }
  }
}

// ---------------- W split+fragment prep ----------------

__global__ void wsplit_kernel(const float* __restrict__ W, uint4* __restrict__ hi4,
                              uint4* __restrict__ lo4) {
  int tid = blockIdx.x * blockDim.x + threadIdx.x;  // 2048 total
  int lane = tid & 63;
  int ks = (tid >> 6) & 3;
  int ct = tid >> 8;
  int col = ct * 16 + (lane & 15);
  int k0 = ks * 32 + ((lane >> 4) << 3);
  uint32 h[8], l[8];
#pragma unroll
  for (int j = 0; j < 8; ++j) {
    float w = W[(size_t)(k0 + j) * DIM + col];
    uint32 hh = bf16_rtne(w);
    float rem = w - bf16_to_f(hh);
    l[j] = bf16_rtne(rem);
    h[j] = hh;
  }
  uint4 H, L;
  H.x = h[0] | (h[1] << 16); H.y = h[2] | (h[3] << 16);
  H.z = h[4] | (h[5] << 16); H.w = h[6] | (h[7] << 16);
  L.x = l[0] | (l[1] << 16); L.y = l[2] | (l[3] << 16);
  L.z = l[4] | (l[5] << 16); L.w = l[6] | (l[7] << 16);
  hi4[tid] = H;
  lo4[tid] = L;
}

// ---------------- split-bf16 MFMA GEMM (+ optional fused 2-col head) ----------------

__launch_bounds__(256, 3)
__global__ void gemm_mfma_kernel(const float* __restrict__ in, const uint4* __restrict__ wHi,
                                 const uint4* __restrict__ wLo, uint32* __restrict__ outb,
                                 int n, const float* __restrict__ rowscale,
                                 const float* __restrict__ bias, float slope, int in_bf16,
                                 const float* __restrict__ headW,
                                 const float* __restrict__ headB,
                                 float* __restrict__ headOut) {
  __shared__ unsigned short sA[2 * 64 * 128];  // hi | lo, XOR-swizzled rows
  __shared__ unsigned short sO[64 * 128];
  int t = threadIdx.x;
  int row0 = blockIdx.x * 64;

  if (in_bf16) {
    const uint4* in4 = (const uint4*)in;
    int q = t & 15;
    int rl = t >> 4;
#pragma unroll
    for (int i = 0; i < 4; ++i) {
      int row = rl + i * 16;
      int grow = row0 + row;
      uint4 v = make_uint4(0, 0, 0, 0);
      if (grow < n) v = in4[(size_t)grow * 16 + q];
      int sidx = (row * 128 + q * 8) ^ ((row & 7) << 3);
      *(uint4*)&sA[sidx] = v;
    }
  } else {
    int quad = t & 31;
    int r = t >> 5;
#pragma unroll
    for (int i = 0; i < 8; ++i) {
      int row = r + i * 8;
      int grow = row0 + row;
      f32x4 v = (f32x4){0.f, 0.f, 0.f, 0.f};
      if (grow < n) v = *(const f32x4*)(in + (size_t)grow * DIM + quad * 4);
      uint32 h0 = bf16_rtne(v.x), h1 = bf16_rtne(v.y), h2 = bf16_rtne(v.z), h3 = bf16_rtne(v.w);
      uint32 l0 = bf16_rtne(v.x - bf16_to_f(h0));
      uint32 l1 = bf16_rtne(v.y - bf16_to_f(h1));
      uint32 l2 = bf16_rtne(v.z - bf16_to_f(h2));
      uint32 l3 = bf16_rtne(v.w - bf16_to_f(h3));
      int sidx = (row * 128 + quad * 4) ^ ((row & 7) << 3);
      *(uint2*)&sA[sidx] = make_uint2(h0 | (h1 << 16), h2 | (h3 << 16));
      *(uint2*)&sA[64 * 128 + sidx] = make_uint2(l0 | (l1 << 16), l2 | (l3 << 16));
    }
  }
  __syncthreads();

  int lane = t & 63;
  int w = t >> 6;
  int rbase = w * 16;
  f32x4 acc[8];
#pragma unroll
  for (int ct = 0; ct < 8; ++ct) acc[ct] = (f32x4){0.f, 0.f, 0.f, 0.f};

  int fragRow = rbase + (lane & 15);
  int fragSwz = (fragRow & 7) << 3;
#pragma unroll
  for (int ks = 0; ks < 4; ++ks) {
    int cidx = ks * 32 + ((lane >> 4) << 3);
    int sidx = (fragRow * 128 + cidx) ^ fragSwz;
    uint4 au = *(uint4*)&sA[sidx];
    short8 ah = __builtin_bit_cast(short8, au);
    short8 al;
    if (!in_bf16) al = __builtin_bit_cast(short8, *(uint4*)&sA[64 * 128 + sidx]);
#pragma unroll
    for (int ct = 0; ct < 8; ++ct) {
      int widx = (ct * 4 + ks) * 64 + lane;
      short8 bh = __builtin_bit_cast(short8, wHi[widx]);
      short8 bl = __builtin_bit_cast(short8, wLo[widx]);
      if (!in_bf16) acc[ct] = __builtin_amdgcn_mfma_f32_16x16x32_bf16(al, bh, acc[ct], 0, 0, 0);
      acc[ct] = __builtin_amdgcn_mfma_f32_16x16x32_bf16(ah, bl, acc[ct], 0, 0, 0);
      acc[ct] = __builtin_amdgcn_mfma_f32_16x16x32_bf16(ah, bh, acc[ct], 0, 0, 0);
    }
  }

  float rs[4];
#pragma unroll
  for (int r = 0; r < 4; ++r) {
    int grow = row0 + rbase + ((lane >> 4) << 2) + r;
    rs[r] = rowscale ? ((grow < n) ? rowscale[grow] : 0.f) : 1.0f;
  }

  float hp0[4] = {0.f, 0.f, 0.f, 0.f};
  float hp1[4] = {0.f, 0.f, 0.f, 0.f};

#pragma unroll
  for (int ct = 0; ct < 8; ++ct) {
    int col = ct * 16 + (lane & 15);
    float bv = bias ? bias[col] : 0.f;
    float hw0 = 0.f, hw1 = 0.f;
    if (headOut) {
      hw0 = headW[col * 2 + 0];
      hw1 = headW[col * 2 + 1];
    }
#pragma unroll
    for (int r = 0; r < 4; ++r) {
      int rowL = rbase + ((lane >> 4) << 2) + r;
      float v = acc[ct][r] * rs[r] + bv;
      v = (v > 0.f) ? v : v * slope;
      if (outb) {
        int sidx = (rowL * 128 + col) ^ ((rowL & 7) << 3);
        sO[sidx] = (unsigned short)bf16_rtne(v);
      }
      if (headOut) {
        hp0[r] = fmaf(v, hw0, hp0[r]);
        hp1[r] = fmaf(v, hw1, hp1[r]);
      }
    }
  }

  if (headOut) {
    float hb0 = headB[0], hb1 = headB[1];
#pragma unroll
    for (int r = 0; r < 4; ++r) {
      float a = hp0[r], b = hp1[r];
#pragma unroll
      for (int off = 8; off; off >>= 1) {
        a += __shfl_xor(a, off);
        b += __shfl_xor(b, off);
      }
      if ((lane & 15) == 0) {
        int grow = row0 + rbase + ((lane >> 4) << 2) + r;
        if (grow < n) {
          float o0 = a + hb0, o1 = b + hb1;
          headOut[2 * (size_t)grow + 0] = (o0 > 0.f) ? o0 : 0.01f * o0;
          headOut[2 * (size_t)grow + 1] = (o1 > 0.f) ? o1 : 0.01f * o1;
        }
      }
    }
  }

  if (outb) {
    __syncthreads();
#pragma unroll
    for (int it = 0; it < 4; ++it) {
      int s = it * 64 + lane;
      int row = rbase + (s >> 4);
      int sin = s & 15;
      int sidx = row * 128 + ((sin * 8) ^ ((row & 7) << 3));
      uint4 v = *(uint4*)&sO[sidx];
      int grow = row0 + row;
      if (grow < n) *(uint4*)(outb + (size_t)grow * 64 + sin * 4) = v;
    }
  }
}

// ---------------- GCN aggregation (bf16 gather, fp32 or bf16 out, optional fused fprob) ----------------

__launch_bounds__(256)
__global__ void agg_kernel(const uint32* __restrict__ g, const int* __restrict__ row_beg,
                           const int* __restrict__ row_end, const int* __restrict__ cols,
                           const float* __restrict__ dinv, const float* __restrict__ bias,
                           void* __restrict__ out, int n, int relu, int out_bf16,
                           const float* __restrict__ fpW, const float* __restrict__ fpB,
                           float* __restrict__ fpOut) {
  int lane = threadIdx.x & 63;
  int node = (blockIdx.x * blockDim.x + threadIdx.x) >> 6;
  if (node >= n) return;
  int beg = row_beg[node];
  int end = row_end[node];
  float ax, ay;
  unpack2(g[(size_t)node * 64 + lane], ax, ay);
  float bx = 0.f, by = 0.f;
  int e = beg;
  for (; e + 16 <= end; e += 16) {
    int s[16];
#pragma unroll
    for (int i = 0; i < 16; ++i) s[i] = cols[e + i];
    uint32 u[16];
#pragma unroll
    for (int i = 0; i < 16; ++i) u[i] = g[(size_t)s[i] * 64 + lane];
#pragma unroll
    for (int i = 0; i < 16; i += 2) {
      float x0, y0, x1, y1;
      unpack2(u[i], x0, y0);
      unpack2(u[i + 1], x1, y1);
      ax += x0; ay += y0;
      bx += x1; by += y1;
    }
  }
  if (e + 8 <= end) {
    int s[8];
#pragma unroll
    for (int i = 0; i < 8; ++i) s[i] = cols[e + i];
    uint32 u[8];
#pragma unroll
    for (int i = 0; i < 8; ++i) u[i] = g[(size_t)s[i] * 64 + lane];
#pragma unroll
    for (int i = 0; i < 8; i += 2) {
      float x0, y0, x1, y1;
      unpack2(u[i], x0, y0);
      unpack2(u[i + 1], x1, y1);
      ax += x0; ay += y0;
      bx += x1; by += y1;
    }
    e += 8;
  }
  for (; e < end; ++e) {
    uint32 u0 = g[(size_t)cols[e] * 64 + lane];
    float x0, y0;
    unpack2(u0, x0, y0);
    ax += x0;
    ay += y0;
  }
  ax += bx;
  ay += by;
  float di = dinv[node];
  float2 bv = ((const float2*)bias)[lane];
  float ox = fmaf(di, ax, bv.x);
  float oy = fmaf(di, ay, bv.y);
  if (relu) {
    ox = fmaxf(ox, 0.f);
    oy = fmaxf(oy, 0.f);
  }
  if (out_bf16) {
    uint32 pk = bf16_rtne(ox) | (bf16_rtne(oy) << 16);
    ((uint32*)out)[(size_t)node * 64 + lane] = pk;
  } else {
    ((float2*)out)[(size_t)node * 64 + lane] = make_float2(ox, oy);
  }

  if (fpOut) {
    float w00 = fpW[(2 * lane) * 2 + 0];
    float w01 = fpW[(2 * lane) * 2 + 1];
    float w10 = fpW[(2 * lane + 1) * 2 + 0];
    float w11 = fpW[(2 * lane + 1) * 2 + 1];
    float p0 = ox * w00 + oy * w10;
    float p1 = ox * w01 + oy * w11;
#pragma unroll
    for (int off = 32; off; off >>= 1) {
      p0 += __shfl_xor(p0, off);
      p1 += __shfl_xor(p1, off);
    }
    if (lane == 0) {
      fpOut[2 * (size_t)node + 0] = p0 + fpB[0];
      fpOut[2 * (size_t)node + 1] = p1 + fpB[1];
    }
  }
}

// ---------------- y heads (both in one launch, bf16 Z) ----------------

__global__ void ydot2_kernel(const uint32* __restrict__ Z,
                             const int* __restrict__ idxA, const float* __restrict__ wA,
                             const float* __restrict__ bA, float* __restrict__ outA,
                             const int* __restrict__ idxB, const float* __restrict__ wB,
                             const float* __restrict__ bB, float* __restrict__ outB,
                             int T) {
  int lane = threadIdx.x & 63;
  int t = (blockIdx.x * blockDim.x + threadIdx.x) >> 6;
  if (t >= 2 * T) return;
  int isB = (t >= T);
  int ti = isB ? (t - T) : t;
  const int* idx = isB ? idxB : idxA;
  const float* w = isB ? wB : wA;
  const float* b = isB ? bB : bA;
  float* o = isB ? outB : outA;
  float2 wv = ((const float2*)w)[lane];
  int node = idx[ti];
  float zx, zy;
  unpack2(Z[(size_t)node * 64 + lane], zx, zy);
  float pp = zx * wv.x + zy * wv.y;
#pragma unroll
  for (int off = 32; off; off >>= 1) pp += __shfl_xor(pp, off);
  if (lane == 0) {
    float v = pp + b[0];
    o[ti] = (v > 0.f) ? v : 0.01f * v;
  }
}

// ---------------- launch ----------------

extern "C" void kernel_launch(void* const* d_in, const int* in_sizes, int n_in,
                              void* d_out, int out_size, void* d_ws, size_t ws_size,
                              hipStream_t stream) {
  const int N = in_sizes[0] / DIM;
  const int E = in_sizes[1] / 2;
  const int T = in_sizes[4];
  const int nb1 = (N + BINN - 1) >> BINSH;          // coarse bins (391)
  const int nA = (E + EPB - 1) / EPB;               // pass-A blocks (391)
  const int binCap = ((E / nb1 + 1024 + 15) / 16) * 16;  // per-bin cols capacity

  const float* x = (const float*)d_in[0];
  const int* ei = (const int*)d_in[1];
  const float* fx = (const float*)d_in[2];
  const int* fei = (const int*)d_in[3];
  const int* treat = (const int*)d_in[4];
  const int* control = (const int*)d_in[5];
  const float* W1 = (const float*)d_in[6];
  const float* b1 = (const float*)d_in[7];
  const float* W2 = (const float*)d_in[8];
  const float* b2 = (const float*)d_in[9];
  const float* Wy1 = (const float*)d_in[10];
  const float* by1 = (const float*)d_in[11];
  const float* Wy0 = (const float*)d_in[12];
  const float* by0 = (const float*)d_in[13];
  const float* Wb = (const float*)d_in[14];
  const float* bb = (const float*)d_in[15];
  const float* Wp1 = (const float*)d_in[16];
  const float* bp1 = (const float*)d_in[17];
  const float* Wp2 = (const float*)d_in[18];
  const float* bp2 = (const float*)d_in[19];

  float* out = (float*)d_out;

  // workspace layout (~95 MB)
  char* p = (char*)d_ws;
  float* bufZ = (float*)p;   p += (size_t)N * DIM * sizeof(float);          // bf16 Z1/Z2 (25.6 MB used) / CSR tmp
  uint32* bufG = (uint32*)p; p += (size_t)N * (DIM / 2) * sizeof(uint32);   // 25.6 MB (bf16 g rows)
  int* cols = (int*)p;       p += (size_t)nb1 * binCap * sizeof(int);       // ~14.4 MB
  int* dir = (int*)p;        p += (size_t)nA * (nb1 + 1) * sizeof(int);     // ~0.6 MB
  int* row_beg = (int*)p;    p += (size_t)(N + 16) * sizeof(int);
  int* row_end = (int*)p;    p += (size_t)(N + 16) * sizeof(int);
  float* dinv = (float*)p;   p += (size_t)(N + 16) * sizeof(float);
  uint4* w1Hi = (uint4*)p;   p += 2048 * sizeof(uint4);
  uint4* w1Lo = (uint4*)p;   p += 2048 * sizeof(uint4);
  uint4* w2Hi = (uint4*)p;   p += 2048 * sizeof(uint4);
  uint4* w2Lo = (uint4*)p;   p += 2048 * sizeof(uint4);
  uint4* wp1Hi = (uint4*)p;  p += 2048 * sizeof(uint4);
  uint4* wp1Lo = (uint4*)p;  p += 2048 * sizeof(uint4);
  uint32* tmp = (uint32*)bufZ;   // 12.8 MB staging aliases bufZ (free during CSR build)

  float* oy1 = out;
  float* oyc0 = out + T;
  float* oy0 = out + 2 * T;
  float* oyc1 = out + 3 * T;
  float* ofp = out + 4 * T;
  float* ofpf = out + 4 * T + 2 * N;
  float* otp = out + 4 * T + 4 * N;
  float* otpf = out + 4 * T + 6 * N;

  wsplit_kernel<<<8, 256, 0, stream>>>(W1, w1Hi, w1Lo);
  wsplit_kernel<<<8, 256, 0, stream>>>(W2, w2Hi, w2Lo);
  wsplit_kernel<<<8, 256, 0, stream>>>(Wp1, wp1Hi, wp1Lo);

  auto run = [&](const float* X, const int* EI,
                 float* y_t, const float* Wt, const float* bt,
                 float* y_c, const float* Wc, const float* bc,
                 float* fp, float* tp) {
    const int* srcp = EI;
    const int* dstp = EI + E;
    // two-pass coalesced CSR build (zero global atomics)
    csr_sort_kernel<<<nA, 256, 0, stream>>>(srcp, dstp, E, nb1, tmp, dir);
    csr_build_kernel<<<nb1, 256, 0, stream>>>(tmp, dir, nA, nb1, N, binCap,
                                              row_beg, row_end, cols, dinv);
    // layer 1: g1 = (X@W1)*dinv (bf16); Z1 = relu(agg) stored bf16 in bufZ
    gemm_mfma_kernel<<<(N + 63) / 64, 256, 0, stream>>>(X, w1Hi, w1Lo, bufG, N, dinv,
                                                        nullptr, 1.0f, 0, nullptr, nullptr, nullptr);
    agg_kernel<<<(N + 3) / 4, 256, 0, stream>>>(bufG, row_beg, row_end, cols, dinv, b1,
                                                (void*)bufZ, N, 1, 1, nullptr, nullptr, nullptr);
    // layer 2: bf16-exact input (2 MFMA); Z2 bf16 + fused fprob (fp32 in-reg)
    gemm_mfma_kernel<<<(N + 63) / 64, 256, 0, stream>>>(bufZ, w2Hi, w2Lo, bufG, N, dinv,
                                                        nullptr, 1.0f, 1, nullptr, nullptr, nullptr);
    agg_kernel<<<(N + 3) / 4, 256, 0, stream>>>(bufG, row_beg, row_end, cols, dinv, b2,
                                                (void*)bufZ, N, 0, 1, Wb, bb, fp);
    // tprob: Wp1 gemm (bf16 Z2 input) with fused stage-2 head, no intermediate write
    gemm_mfma_kernel<<<(N + 63) / 64, 256, 0, stream>>>(bufZ, wp1Hi, wp1Lo, nullptr, N, nullptr,
                                                        bp1, 0.01f, 1, Wp2, bp2, tp);
    // y heads (both in one launch)
    ydot2_kernel<<<(2 * T + 3) / 4, 256, 0, stream>>>((const uint32*)bufZ,
                                                      treat, Wt, bt, y_t,
                                                      control, Wc, bc, y_c, T);
  };

  run(x, ei, oy1, Wy1, by1, oy0, Wy0, by0, ofp, otp);
  run(fx, fei, oyc0, Wy0, by0, oyc1, Wy1, by1, ofpf, otpf);
}

// Round 14
// 862.627 us; speedup vs baseline: 1.2477x; 1.2477x over previous
//
#include <hip/hip_runtime.h>

#define DIM 128
#define EPB 8192              // edges per pass-A block
#define BINSH 8               // coarse bin = 256 consecutive node ids
#define BINN 256

typedef unsigned int uint32;
typedef __attribute__((ext_vector_type(8))) short short8;
typedef __attribute__((ext_vector_type(4))) float f32x4;

__device__ __forceinline__ uint32 bf16_rtne(float f) {
  uint32 u = __float_as_uint(f);
  return (u + 0x7FFFu + ((u >> 16) & 1u)) >> 16;
}
__device__ __forceinline__ float bf16_to_f(uint32 h) { return __uint_as_float(h << 16); }
__device__ __forceinline__ void unpack2(uint32 u, float& x, float& y) {
  x = __uint_as_float(u << 16);
  y = __uint_as_float(u & 0xFFFF0000u);
}

// ---------------- CSR build pass A: in-LDS counting sort by coarse bin ----------------

__launch_bounds__(256)
__global__ void csr_sort_kernel(const int* __restrict__ src, const int* __restrict__ dst,
                                int E, int nb1, uint32* __restrict__ tmp,
                                int* __restrict__ dir) {
  __shared__ uint32 sorted[EPB];       // 32 KB
  __shared__ int lcnt[512];
  __shared__ int lbase[512];
  __shared__ int ps[256];
  int t = threadIdx.x;
  int base = blockIdx.x * EPB;

  lcnt[t] = 0;
  lcnt[t + 256] = 0;
  __syncthreads();

  uint32 val[32];
  uint32 br[32];   // (bin<<13) | rank
#pragma unroll
  for (int i = 0; i < 32; ++i) {
    int e = base + i * 256 + t;
    if (e < E) {
      int d = __builtin_nontemporal_load(dst + e);
      int s = __builtin_nontemporal_load(src + e);
      int bin = d >> BINSH;
      val[i] = ((uint32)s << BINSH) | (uint32)(d & (BINN - 1));
      int rank = atomicAdd(&lcnt[bin], 1);
      br[i] = ((uint32)bin << 13) | (uint32)rank;
    } else {
      br[i] = 0xFFFFFFFFu;
    }
  }
  __syncthreads();

  {
    int a0 = lcnt[2 * t], a1 = lcnt[2 * t + 1];
    int psum = a0 + a1;
    ps[t] = psum;
    __syncthreads();
    for (int off = 1; off < 256; off <<= 1) {
      int x = (t >= off) ? ps[t - off] : 0;
      __syncthreads();
      ps[t] += x;
      __syncthreads();
    }
    int ebase = ps[t] - psum;
    lbase[2 * t] = ebase;
    lbase[2 * t + 1] = ebase + a0;
  }
  __syncthreads();

#pragma unroll
  for (int i = 0; i < 32; ++i) {
    if (br[i] != 0xFFFFFFFFu) {
      int bin = br[i] >> 13;
      int rank = br[i] & 0x1FFF;
      sorted[lbase[bin] + rank] = val[i];
    }
  }
  __syncthreads();

  int cnt = min(EPB, E - base);
#pragma unroll
  for (int i = 0; i < 32; ++i) {
    int idx = i * 256 + t;
    if (idx < cnt) tmp[base + idx] = sorted[idx];
  }
  for (int b = t; b <= nb1; b += 256) {
    dir[blockIdx.x * (nb1 + 1) + b] = lbase[b];
  }
}

// ---------------- CSR build pass B: one block per bin (R12 form — fast) ----------------

__launch_bounds__(256)
__global__ void csr_build_kernel(const uint32* __restrict__ tmp, const int* __restrict__ dir,
                                 int nA, int nb1, int N, int binCap,
                                 int* __restrict__ row_beg, int* __restrict__ row_end,
                                 int* __restrict__ cols, float* __restrict__ dinv) {
  __shared__ int rbeg[512];
  __shared__ int rend[512];
  __shared__ int deg[BINN];
  __shared__ int cur[BINN];
  __shared__ int ps[256];
  int j = blockIdx.x;
  int t = threadIdx.x;
  int node0 = j << BINSH;
  int colsBase = j * binCap;

  if (t < BINN) deg[t] = 0;
  for (int i = t; i < nA; i += 256) {
    rbeg[i] = dir[i * (nb1 + 1) + j];
    rend[i] = dir[i * (nb1 + 1) + j + 1];
  }
  __syncthreads();

  // phase 1: degree histogram
  for (int i = t; i < nA; i += 256) {
    int b = rbeg[i], en = rend[i];
    for (int q = b; q < en; ++q) {
      atomicAdd(&deg[tmp[(size_t)i * EPB + q] & (BINN - 1)], 1);
    }
  }
  __syncthreads();

  // exclusive scan over deg[0..255]
  int dv = deg[t];
  ps[t] = dv;
  __syncthreads();
  for (int off = 1; off < 256; off <<= 1) {
    int x = (t >= off) ? ps[t - off] : 0;
    __syncthreads();
    ps[t] += x;
    __syncthreads();
  }
  int ebase = ps[t] - dv;
  cur[t] = ebase;
  int node = node0 + t;
  if (node < N) {
    row_beg[node] = colsBase + ebase;
    row_end[node] = colsBase + ebase + dv;
    dinv[node] = rsqrtf((float)dv + 1.0f);
  }
  __syncthreads();

  // phase 2: scatter src into this bin's cols window (L2-resident, ~36 KB)
  for (int i = t; i < nA; i += 256) {
    int b = rbeg[i], en = rend[i];
    for (int q = b; q < en; ++q) {
      uint32 v = tmp[(size_t)i * EPB + q];
      int p = atomicAdd(&cur[v & (BINN - 1)], 1);
      cols[colsBase + p] = (int)(v >> BINSH);
    }
  }
}

// ---------------- W split+fragment prep ----------------

__global__ void wsplit_kernel(const float* __restrict__ W, uint4* __restrict__ hi4,
                              uint4* __restrict__ lo4) {
  int tid = blockIdx.x * blockDim.x + threadIdx.x;  // 2048 total
  int lane = tid & 63;
  int ks = (tid >> 6) & 3;
  int ct = tid >> 8;
  int col = ct * 16 + (lane & 15);
  int k0 = ks * 32 + ((lane >> 4) << 3);
  uint32 h[8], l[8];
#pragma unroll
  for (int j = 0; j < 8; ++j) {
    float w = W[(size_t)(k0 + j) * DIM + col];
    uint32 hh = bf16_rtne(w);
    float rem = w - bf16_to_f(hh);
    l[j] = bf16_rtne(rem);
    h[j] = hh;
  }
  uint4 H, L;
  H.x = h[0] | (h[1] << 16); H.y = h[2] | (h[3] << 16);
  H.z = h[4] | (h[5] << 16); H.w = h[6] | (h[7] << 16);
  L.x = l[0] | (l[1] << 16); L.y = l[2] | (l[3] << 16);
  L.z = l[4] | (l[5] << 16); L.w = l[6] | (l[7] << 16);
  hi4[tid] = H;
  lo4[tid] = L;
}

// ---------------- split-bf16 MFMA GEMM (+ optional fused 2-col head) ----------------

__launch_bounds__(256, 3)
__global__ void gemm_mfma_kernel(const float* __restrict__ in, const uint4* __restrict__ wHi,
                                 const uint4* __restrict__ wLo, uint32* __restrict__ outb,
                                 int n, const float* __restrict__ rowscale,
                                 const float* __restrict__ bias, float slope, int in_bf16,
                                 const float* __restrict__ headW,
                                 const float* __restrict__ headB,
                                 float* __restrict__ headOut) {
  __shared__ unsigned short sA[2 * 64 * 128];  // hi | lo, XOR-swizzled rows
  __shared__ unsigned short sO[64 * 128];
  int t = threadIdx.x;
  int row0 = blockIdx.x * 64;

  if (in_bf16) {
    const uint4* in4 = (const uint4*)in;
    int q = t & 15;
    int rl = t >> 4;
#pragma unroll
    for (int i = 0; i < 4; ++i) {
      int row = rl + i * 16;
      int grow = row0 + row;
      uint4 v = make_uint4(0, 0, 0, 0);
      if (grow < n) v = in4[(size_t)grow * 16 + q];
      int sidx = (row * 128 + q * 8) ^ ((row & 7) << 3);
      *(uint4*)&sA[sidx] = v;
    }
  } else {
    int quad = t & 31;
    int r = t >> 5;
#pragma unroll
    for (int i = 0; i < 8; ++i) {
      int row = r + i * 8;
      int grow = row0 + row;
      f32x4 v = (f32x4){0.f, 0.f, 0.f, 0.f};
      if (grow < n) v = *(const f32x4*)(in + (size_t)grow * DIM + quad * 4);
      uint32 h0 = bf16_rtne(v.x), h1 = bf16_rtne(v.y), h2 = bf16_rtne(v.z), h3 = bf16_rtne(v.w);
      uint32 l0 = bf16_rtne(v.x - bf16_to_f(h0));
      uint32 l1 = bf16_rtne(v.y - bf16_to_f(h1));
      uint32 l2 = bf16_rtne(v.z - bf16_to_f(h2));
      uint32 l3 = bf16_rtne(v.w - bf16_to_f(h3));
      int sidx = (row * 128 + quad * 4) ^ ((row & 7) << 3);
      *(uint2*)&sA[sidx] = make_uint2(h0 | (h1 << 16), h2 | (h3 << 16));
      *(uint2*)&sA[64 * 128 + sidx] = make_uint2(l0 | (l1 << 16), l2 | (l3 << 16));
    }
  }
  __syncthreads();

  int lane = t & 63;
  int w = t >> 6;
  int rbase = w * 16;
  f32x4 acc[8];
#pragma unroll
  for (int ct = 0; ct < 8; ++ct) acc[ct] = (f32x4){0.f, 0.f, 0.f, 0.f};

  int fragRow = rbase + (lane & 15);
  int fragSwz = (fragRow & 7) << 3;
#pragma unroll
  for (int ks = 0; ks < 4; ++ks) {
    int cidx = ks * 32 + ((lane >> 4) << 3);
    int sidx = (fragRow * 128 + cidx) ^ fragSwz;
    uint4 au = *(uint4*)&sA[sidx];
    short8 ah = __builtin_bit_cast(short8, au);
    short8 al;
    if (!in_bf16) al = __builtin_bit_cast(short8, *(uint4*)&sA[64 * 128 + sidx]);
#pragma unroll
    for (int ct = 0; ct < 8; ++ct) {
      int widx = (ct * 4 + ks) * 64 + lane;
      short8 bh = __builtin_bit_cast(short8, wHi[widx]);
      short8 bl = __builtin_bit_cast(short8, wLo[widx]);
      if (!in_bf16) acc[ct] = __builtin_amdgcn_mfma_f32_16x16x32_bf16(al, bh, acc[ct], 0, 0, 0);
      acc[ct] = __builtin_amdgcn_mfma_f32_16x16x32_bf16(ah, bl, acc[ct], 0, 0, 0);
      acc[ct] = __builtin_amdgcn_mfma_f32_16x16x32_bf16(ah, bh, acc[ct], 0, 0, 0);
    }
  }

  float rs[4];
#pragma unroll
  for (int r = 0; r < 4; ++r) {
    int grow = row0 + rbase + ((lane >> 4) << 2) + r;
    rs[r] = rowscale ? ((grow < n) ? rowscale[grow] : 0.f) : 1.0f;
  }

  float hp0[4] = {0.f, 0.f, 0.f, 0.f};
  float hp1[4] = {0.f, 0.f, 0.f, 0.f};

#pragma unroll
  for (int ct = 0; ct < 8; ++ct) {
    int col = ct * 16 + (lane & 15);
    float bv = bias ? bias[col] : 0.f;
    float hw0 = 0.f, hw1 = 0.f;
    if (headOut) {
      hw0 = headW[col * 2 + 0];
      hw1 = headW[col * 2 + 1];
    }
#pragma unroll
    for (int r = 0; r < 4; ++r) {
      int rowL = rbase + ((lane >> 4) << 2) + r;
      float v = acc[ct][r] * rs[r] + bv;
      v = (v > 0.f) ? v : v * slope;
      if (outb) {
        int sidx = (rowL * 128 + col) ^ ((rowL & 7) << 3);
        sO[sidx] = (unsigned short)bf16_rtne(v);
      }
      if (headOut) {
        hp0[r] = fmaf(v, hw0, hp0[r]);
        hp1[r] = fmaf(v, hw1, hp1[r]);
      }
    }
  }

  if (headOut) {
    float hb0 = headB[0], hb1 = headB[1];
#pragma unroll
    for (int r = 0; r < 4; ++r) {
      float a = hp0[r], b = hp1[r];
#pragma unroll
      for (int off = 8; off; off >>= 1) {
        a += __shfl_xor(a, off);
        b += __shfl_xor(b, off);
      }
      if ((lane & 15) == 0) {
        int grow = row0 + rbase + ((lane >> 4) << 2) + r;
        if (grow < n) {
          float o0 = a + hb0, o1 = b + hb1;
          headOut[2 * (size_t)grow + 0] = (o0 > 0.f) ? o0 : 0.01f * o0;
          headOut[2 * (size_t)grow + 1] = (o1 > 0.f) ? o1 : 0.01f * o1;
        }
      }
    }
  }

  if (outb) {
    __syncthreads();
#pragma unroll
    for (int it = 0; it < 4; ++it) {
      int s = it * 64 + lane;
      int row = rbase + (s >> 4);
      int sin = s & 15;
      int sidx = row * 128 + ((sin * 8) ^ ((row & 7) << 3));
      uint4 v = *(uint4*)&sO[sidx];
      int grow = row0 + row;
      if (grow < n) *(uint4*)(outb + (size_t)grow * 64 + sin * 4) = v;
    }
  }
}

// ---------------- GCN aggregation (bf16 gather, fp32 or bf16 out, optional fused fprob) ----------------

__launch_bounds__(256)
__global__ void agg_kernel(const uint32* __restrict__ g, const int* __restrict__ row_beg,
                           const int* __restrict__ row_end, const int* __restrict__ cols,
                           const float* __restrict__ dinv, const float* __restrict__ bias,
                           void* __restrict__ out, int n, int relu, int out_bf16,
                           const float* __restrict__ fpW, const float* __restrict__ fpB,
                           float* __restrict__ fpOut) {
  int lane = threadIdx.x & 63;
  int node = (blockIdx.x * blockDim.x + threadIdx.x) >> 6;
  if (node >= n) return;
  int beg = row_beg[node];
  int end = row_end[node];
  float ax, ay;
  unpack2(g[(size_t)node * 64 + lane], ax, ay);
  float bx = 0.f, by = 0.f;
  int e = beg;
  for (; e + 16 <= end; e += 16) {
    int s[16];
#pragma unroll
    for (int i = 0; i < 16; ++i) s[i] = cols[e + i];
    uint32 u[16];
#pragma unroll
    for (int i = 0; i < 16; ++i) u[i] = g[(size_t)s[i] * 64 + lane];
#pragma unroll
    for (int i = 0; i < 16; i += 2) {
      float x0, y0, x1, y1;
      unpack2(u[i], x0, y0);
      unpack2(u[i + 1], x1, y1);
      ax += x0; ay += y0;
      bx += x1; by += y1;
    }
  }
  if (e + 8 <= end) {
    int s[8];
#pragma unroll
    for (int i = 0; i < 8; ++i) s[i] = cols[e + i];
    uint32 u[8];
#pragma unroll
    for (int i = 0; i < 8; ++i) u[i] = g[(size_t)s[i] * 64 + lane];
#pragma unroll
    for (int i = 0; i < 8; i += 2) {
      float x0, y0, x1, y1;
      unpack2(u[i], x0, y0);
      unpack2(u[i + 1], x1, y1);
      ax += x0; ay += y0;
      bx += x1; by += y1;
    }
    e += 8;
  }
  for (; e < end; ++e) {
    uint32 u0 = g[(size_t)cols[e] * 64 + lane];
    float x0, y0;
    unpack2(u0, x0, y0);
    ax += x0;
    ay += y0;
  }
  ax += bx;
  ay += by;
  float di = dinv[node];
  float2 bv = ((const float2*)bias)[lane];
  float ox = fmaf(di, ax, bv.x);
  float oy = fmaf(di, ay, bv.y);
  if (relu) {
    ox = fmaxf(ox, 0.f);
    oy = fmaxf(oy, 0.f);
  }
  if (out_bf16) {
    uint32 pk = bf16_rtne(ox) | (bf16_rtne(oy) << 16);
    ((uint32*)out)[(size_t)node * 64 + lane] = pk;
  } else {
    ((float2*)out)[(size_t)node * 64 + lane] = make_float2(ox, oy);
  }

  if (fpOut) {
    float w00 = fpW[(2 * lane) * 2 + 0];
    float w01 = fpW[(2 * lane) * 2 + 1];
    float w10 = fpW[(2 * lane + 1) * 2 + 0];
    float w11 = fpW[(2 * lane + 1) * 2 + 1];
    float p0 = ox * w00 + oy * w10;
    float p1 = ox * w01 + oy * w11;
#pragma unroll
    for (int off = 32; off; off >>= 1) {
      p0 += __shfl_xor(p0, off);
      p1 += __shfl_xor(p1, off);
    }
    if (lane == 0) {
      fpOut[2 * (size_t)node + 0] = p0 + fpB[0];
      fpOut[2 * (size_t)node + 1] = p1 + fpB[1];
    }
  }
}

// ---------------- y heads (both in one launch, bf16 Z) ----------------

__global__ void ydot2_kernel(const uint32* __restrict__ Z,
                             const int* __restrict__ idxA, const float* __restrict__ wA,
                             const float* __restrict__ bA, float* __restrict__ outA,
                             const int* __restrict__ idxB, const float* __restrict__ wB,
                             const float* __restrict__ bB, float* __restrict__ outB,
                             int T) {
  int lane = threadIdx.x & 63;
  int t = (blockIdx.x * blockDim.x + threadIdx.x) >> 6;
  if (t >= 2 * T) return;
  int isB = (t >= T);
  int ti = isB ? (t - T) : t;
  const int* idx = isB ? idxB : idxA;
  const float* w = isB ? wB : wA;
  const float* b = isB ? bB : bA;
  float* o = isB ? outB : outA;
  float2 wv = ((const float2*)w)[lane];
  int node = idx[ti];
  float zx, zy;
  unpack2(Z[(size_t)node * 64 + lane], zx, zy);
  float pp = zx * wv.x + zy * wv.y;
#pragma unroll
  for (int off = 32; off; off >>= 1) pp += __shfl_xor(pp, off);
  if (lane == 0) {
    float v = pp + b[0];
    o[ti] = (v > 0.f) ? v : 0.01f * v;
  }
}

// ---------------- launch ----------------

extern "C" void kernel_launch(void* const* d_in, const int* in_sizes, int n_in,
                              void* d_out, int out_size, void* d_ws, size_t ws_size,
                              hipStream_t stream) {
  const int N = in_sizes[0] / DIM;
  const int E = in_sizes[1] / 2;
  const int T = in_sizes[4];
  const int nb1 = (N + BINN - 1) >> BINSH;          // coarse bins (391)
  const int nA = (E + EPB - 1) / EPB;               // pass-A blocks (391)
  const int binCap = ((E / nb1 + 1024 + 15) / 16) * 16;  // per-bin cols capacity

  const float* x = (const float*)d_in[0];
  const int* ei = (const int*)d_in[1];
  const float* fx = (const float*)d_in[2];
  const int* fei = (const int*)d_in[3];
  const int* treat = (const int*)d_in[4];
  const int* control = (const int*)d_in[5];
  const float* W1 = (const float*)d_in[6];
  const float* b1 = (const float*)d_in[7];
  const float* W2 = (const float*)d_in[8];
  const float* b2 = (const float*)d_in[9];
  const float* Wy1 = (const float*)d_in[10];
  const float* by1 = (const float*)d_in[11];
  const float* Wy0 = (const float*)d_in[12];
  const float* by0 = (const float*)d_in[13];
  const float* Wb = (const float*)d_in[14];
  const float* bb = (const float*)d_in[15];
  const float* Wp1 = (const float*)d_in[16];
  const float* bp1 = (const float*)d_in[17];
  const float* Wp2 = (const float*)d_in[18];
  const float* bp2 = (const float*)d_in[19];

  float* out = (float*)d_out;

  // workspace layout (~95 MB)
  char* p = (char*)d_ws;
  float* bufZ = (float*)p;   p += (size_t)N * DIM * sizeof(float);          // bf16 Z1/Z2 (25.6 MB used) / CSR tmp
  uint32* bufG = (uint32*)p; p += (size_t)N * (DIM / 2) * sizeof(uint32);   // 25.6 MB (bf16 g rows)
  int* cols = (int*)p;       p += (size_t)nb1 * binCap * sizeof(int);       // ~14.4 MB
  int* dir = (int*)p;        p += (size_t)nA * (nb1 + 1) * sizeof(int);     // ~0.6 MB
  int* row_beg = (int*)p;    p += (size_t)(N + 16) * sizeof(int);
  int* row_end = (int*)p;    p += (size_t)(N + 16) * sizeof(int);
  float* dinv = (float*)p;   p += (size_t)(N + 16) * sizeof(float);
  uint4* w1Hi = (uint4*)p;   p += 2048 * sizeof(uint4);
  uint4* w1Lo = (uint4*)p;   p += 2048 * sizeof(uint4);
  uint4* w2Hi = (uint4*)p;   p += 2048 * sizeof(uint4);
  uint4* w2Lo = (uint4*)p;   p += 2048 * sizeof(uint4);
  uint4* wp1Hi = (uint4*)p;  p += 2048 * sizeof(uint4);
  uint4* wp1Lo = (uint4*)p;  p += 2048 * sizeof(uint4);
  uint32* tmp = (uint32*)bufZ;   // 12.8 MB staging aliases bufZ (free during CSR build)

  float* oy1 = out;
  float* oyc0 = out + T;
  float* oy0 = out + 2 * T;
  float* oyc1 = out + 3 * T;
  float* ofp = out + 4 * T;
  float* ofpf = out + 4 * T + 2 * N;
  float* otp = out + 4 * T + 4 * N;
  float* otpf = out + 4 * T + 6 * N;

  wsplit_kernel<<<8, 256, 0, stream>>>(W1, w1Hi, w1Lo);
  wsplit_kernel<<<8, 256, 0, stream>>>(W2, w2Hi, w2Lo);
  wsplit_kernel<<<8, 256, 0, stream>>>(Wp1, wp1Hi, wp1Lo);

  auto run = [&](const float* X, const int* EI,
                 float* y_t, const float* Wt, const float* bt,
                 float* y_c, const float* Wc, const float* bc,
                 float* fp, float* tp) {
    const int* srcp = EI;
    const int* dstp = EI + E;
    // two-pass coalesced CSR build (zero global atomics)
    csr_sort_kernel<<<nA, 256, 0, stream>>>(srcp, dstp, E, nb1, tmp, dir);
    csr_build_kernel<<<nb1, 256, 0, stream>>>(tmp, dir, nA, nb1, N, binCap,
                                              row_beg, row_end, cols, dinv);
    // layer 1: g1 = (X@W1)*dinv (bf16); Z1 = relu(agg) stored bf16 in bufZ
    gemm_mfma_kernel<<<(N + 63) / 64, 256, 0, stream>>>(X, w1Hi, w1Lo, bufG, N, dinv,
                                                        nullptr, 1.0f, 0, nullptr, nullptr, nullptr);
    agg_kernel<<<(N + 3) / 4, 256, 0, stream>>>(bufG, row_beg, row_end, cols, dinv, b1,
                                                (void*)bufZ, N, 1, 1, nullptr, nullptr, nullptr);
    // layer 2: bf16-exact input (2 MFMA); Z2 bf16 + fused fprob (fp32 in-reg)
    gemm_mfma_kernel<<<(N + 63) / 64, 256, 0, stream>>>(bufZ, w2Hi, w2Lo, bufG, N, dinv,
                                                        nullptr, 1.0f, 1, nullptr, nullptr, nullptr);
    agg_kernel<<<(N + 3) / 4, 256, 0, stream>>>(bufG, row_beg, row_end, cols, dinv, b2,
                                                (void*)bufZ, N, 0, 1, Wb, bb, fp);
    // tprob: Wp1 gemm (bf16 Z2 input) with fused stage-2 head, no intermediate write
    gemm_mfma_kernel<<<(N + 63) / 64, 256, 0, stream>>>(bufZ, wp1Hi, wp1Lo, nullptr, N, nullptr,
                                                        bp1, 0.01f, 1, Wp2, bp2, tp);
    // y heads (both in one launch)
    ydot2_kernel<<<(2 * T + 3) / 4, 256, 0, stream>>>((const uint32*)bufZ,
                                                      treat, Wt, bt, y_t,
                                                      control, Wc, bc, y_c, T);
  };

  run(x, ei, oy1, Wy1, by1, oy0, Wy0, by0, ofp, otp);
  run(fx, fei, oyc0, Wy0, by0, oyc1, Wy1, by1, ofpf, otpf);
}

// Round 15
// 848.963 us; speedup vs baseline: 1.2678x; 1.0161x over previous
//
#include <hip/hip_runtime.h>

#define DIM 128
#define EPB 8192              // edges per pass-A block
#define BINSH 8               // coarse bin = 256 consecutive node ids
#define BINN 256

typedef unsigned int uint32;
typedef __attribute__((ext_vector_type(8))) short short8;
typedef __attribute__((ext_vector_type(4))) float f32x4;

__device__ __forceinline__ uint32 bf16_rtne(float f) {
  uint32 u = __float_as_uint(f);
  return (u + 0x7FFFu + ((u >> 16) & 1u)) >> 16;
}
__device__ __forceinline__ float bf16_to_f(uint32 h) { return __uint_as_float(h << 16); }
__device__ __forceinline__ float lo16f(uint32 u) { return __uint_as_float(u << 16); }
__device__ __forceinline__ float hi16f(uint32 u) { return __uint_as_float(u & 0xFFFF0000u); }
__device__ __forceinline__ void unpack2(uint32 u, float& x, float& y) {
  x = __uint_as_float(u << 16);
  y = __uint_as_float(u & 0xFFFF0000u);
}

// ---------------- CSR build pass A: in-LDS counting sort by coarse bin ----------------

__launch_bounds__(256)
__global__ void csr_sort_kernel(const int* __restrict__ src, const int* __restrict__ dst,
                                int E, int nb1, uint32* __restrict__ tmp,
                                int* __restrict__ dir) {
  __shared__ uint32 sorted[EPB];       // 32 KB
  __shared__ int lcnt[512];
  __shared__ int lbase[512];
  __shared__ int ps[256];
  int t = threadIdx.x;
  int base = blockIdx.x * EPB;

  lcnt[t] = 0;
  lcnt[t + 256] = 0;
  __syncthreads();

  uint32 val[32];
  uint32 br[32];   // (bin<<13) | rank
#pragma unroll
  for (int i = 0; i < 32; ++i) {
    int e = base + i * 256 + t;
    if (e < E) {
      int d = __builtin_nontemporal_load(dst + e);
      int s = __builtin_nontemporal_load(src + e);
      int bin = d >> BINSH;
      val[i] = ((uint32)s << BINSH) | (uint32)(d & (BINN - 1));
      int rank = atomicAdd(&lcnt[bin], 1);
      br[i] = ((uint32)bin << 13) | (uint32)rank;
    } else {
      br[i] = 0xFFFFFFFFu;
    }
  }
  __syncthreads();

  {
    int a0 = lcnt[2 * t], a1 = lcnt[2 * t + 1];
    int psum = a0 + a1;
    ps[t] = psum;
    __syncthreads();
    for (int off = 1; off < 256; off <<= 1) {
      int x = (t >= off) ? ps[t - off] : 0;
      __syncthreads();
      ps[t] += x;
      __syncthreads();
    }
    int ebase = ps[t] - psum;
    lbase[2 * t] = ebase;
    lbase[2 * t + 1] = ebase + a0;
  }
  __syncthreads();

#pragma unroll
  for (int i = 0; i < 32; ++i) {
    if (br[i] != 0xFFFFFFFFu) {
      int bin = br[i] >> 13;
      int rank = br[i] & 0x1FFF;
      sorted[lbase[bin] + rank] = val[i];
    }
  }
  __syncthreads();

  int cnt = min(EPB, E - base);
#pragma unroll
  for (int i = 0; i < 32; ++i) {
    int idx = i * 256 + t;
    if (idx < cnt) tmp[base + idx] = sorted[idx];
  }
  for (int b = t; b <= nb1; b += 256) {
    dir[blockIdx.x * (nb1 + 1) + b] = lbase[b];
  }
}

// ---------------- CSR build pass B: one block per bin (R12 form — fast) ----------------

__launch_bounds__(256)
__global__ void csr_build_kernel(const uint32* __restrict__ tmp, const int* __restrict__ dir,
                                 int nA, int nb1, int N, int binCap,
                                 int* __restrict__ row_beg, int* __restrict__ row_end,
                                 int* __restrict__ cols, float* __restrict__ dinv) {
  __shared__ int rbeg[512];
  __shared__ int rend[512];
  __shared__ int deg[BINN];
  __shared__ int cur[BINN];
  __shared__ int ps[256];
  int j = blockIdx.x;
  int t = threadIdx.x;
  int node0 = j << BINSH;
  int colsBase = j * binCap;

  if (t < BINN) deg[t] = 0;
  for (int i = t; i < nA; i += 256) {
    rbeg[i] = dir[i * (nb1 + 1) + j];
    rend[i] = dir[i * (nb1 + 1) + j + 1];
  }
  __syncthreads();

  // phase 1: degree histogram
  for (int i = t; i < nA; i += 256) {
    int b = rbeg[i], en = rend[i];
    for (int q = b; q < en; ++q) {
      atomicAdd(&deg[tmp[(size_t)i * EPB + q] & (BINN - 1)], 1);
    }
  }
  __syncthreads();

  // exclusive scan over deg[0..255]
  int dv = deg[t];
  ps[t] = dv;
  __syncthreads();
  for (int off = 1; off < 256; off <<= 1) {
    int x = (t >= off) ? ps[t - off] : 0;
    __syncthreads();
    ps[t] += x;
    __syncthreads();
  }
  int ebase = ps[t] - dv;
  cur[t] = ebase;
  int node = node0 + t;
  if (node < N) {
    row_beg[node] = colsBase + ebase;
    row_end[node] = colsBase + ebase + dv;
    dinv[node] = rsqrtf((float)dv + 1.0f);
  }
  __syncthreads();

  // phase 2: scatter src into this bin's cols window (L2-resident, ~36 KB)
  for (int i = t; i < nA; i += 256) {
    int b = rbeg[i], en = rend[i];
    for (int q = b; q < en; ++q) {
      uint32 v = tmp[(size_t)i * EPB + q];
      int p = atomicAdd(&cur[v & (BINN - 1)], 1);
      cols[colsBase + p] = (int)(v >> BINSH);
    }
  }
}

// ---------------- W split+fragment prep (3 matrices, one launch) ----------------

__global__ void wsplit3_kernel(const float* __restrict__ Wa, uint4* __restrict__ hiA, uint4* __restrict__ loA,
                               const float* __restrict__ Wb, uint4* __restrict__ hiB, uint4* __restrict__ loB,
                               const float* __restrict__ Wc, uint4* __restrict__ hiC, uint4* __restrict__ loC) {
  int widx = blockIdx.x >> 3;
  int tid = (blockIdx.x & 7) * 256 + threadIdx.x;  // 0..2047
  const float* W = (widx == 0) ? Wa : (widx == 1) ? Wb : Wc;
  uint4* hi4 = (widx == 0) ? hiA : (widx == 1) ? hiB : hiC;
  uint4* lo4 = (widx == 0) ? loA : (widx == 1) ? loB : loC;
  int lane = tid & 63;
  int ks = (tid >> 6) & 3;
  int ct = tid >> 8;
  int col = ct * 16 + (lane & 15);
  int k0 = ks * 32 + ((lane >> 4) << 3);
  uint32 h[8], l[8];
#pragma unroll
  for (int j = 0; j < 8; ++j) {
    float w = W[(size_t)(k0 + j) * DIM + col];
    uint32 hh = bf16_rtne(w);
    float rem = w - bf16_to_f(hh);
    l[j] = bf16_rtne(rem);
    h[j] = hh;
  }
  uint4 H, L;
  H.x = h[0] | (h[1] << 16); H.y = h[2] | (h[3] << 16);
  H.z = h[4] | (h[5] << 16); H.w = h[6] | (h[7] << 16);
  L.x = l[0] | (l[1] << 16); L.y = l[2] | (l[3] << 16);
  L.z = l[4] | (l[5] << 16); L.w = l[6] | (l[7] << 16);
  hi4[tid] = H;
  lo4[tid] = L;
}

// ---------------- split-bf16 MFMA GEMM (+ optional fused 2-col head) ----------------

__launch_bounds__(256, 3)
__global__ void gemm_mfma_kernel(const float* __restrict__ in, const uint4* __restrict__ wHi,
                                 const uint4* __restrict__ wLo, uint32* __restrict__ outb,
                                 int n, const float* __restrict__ rowscale,
                                 const float* __restrict__ bias, float slope, int in_bf16,
                                 const float* __restrict__ headW,
                                 const float* __restrict__ headB,
                                 float* __restrict__ headOut) {
  __shared__ unsigned short sA[2 * 64 * 128];  // hi | lo, XOR-swizzled rows
  __shared__ unsigned short sO[64 * 128];
  int t = threadIdx.x;
  int row0 = blockIdx.x * 64;

  if (in_bf16) {
    const uint4* in4 = (const uint4*)in;
    int q = t & 15;
    int rl = t >> 4;
#pragma unroll
    for (int i = 0; i < 4; ++i) {
      int row = rl + i * 16;
      int grow = row0 + row;
      uint4 v = make_uint4(0, 0, 0, 0);
      if (grow < n) v = in4[(size_t)grow * 16 + q];
      int sidx = (row * 128 + q * 8) ^ ((row & 7) << 3);
      *(uint4*)&sA[sidx] = v;
    }
  } else {
    int quad = t & 31;
    int r = t >> 5;
#pragma unroll
    for (int i = 0; i < 8; ++i) {
      int row = r + i * 8;
      int grow = row0 + row;
      f32x4 v = (f32x4){0.f, 0.f, 0.f, 0.f};
      if (grow < n) v = *(const f32x4*)(in + (size_t)grow * DIM + quad * 4);
      uint32 h0 = bf16_rtne(v.x), h1 = bf16_rtne(v.y), h2 = bf16_rtne(v.z), h3 = bf16_rtne(v.w);
      uint32 l0 = bf16_rtne(v.x - bf16_to_f(h0));
      uint32 l1 = bf16_rtne(v.y - bf16_to_f(h1));
      uint32 l2 = bf16_rtne(v.z - bf16_to_f(h2));
      uint32 l3 = bf16_rtne(v.w - bf16_to_f(h3));
      int sidx = (row * 128 + quad * 4) ^ ((row & 7) << 3);
      *(uint2*)&sA[sidx] = make_uint2(h0 | (h1 << 16), h2 | (h3 << 16));
      *(uint2*)&sA[64 * 128 + sidx] = make_uint2(l0 | (l1 << 16), l2 | (l3 << 16));
    }
  }
  __syncthreads();

  int lane = t & 63;
  int w = t >> 6;
  int rbase = w * 16;
  f32x4 acc[8];
#pragma unroll
  for (int ct = 0; ct < 8; ++ct) acc[ct] = (f32x4){0.f, 0.f, 0.f, 0.f};

  int fragRow = rbase + (lane & 15);
  int fragSwz = (fragRow & 7) << 3;
#pragma unroll
  for (int ks = 0; ks < 4; ++ks) {
    int cidx = ks * 32 + ((lane >> 4) << 3);
    int sidx = (fragRow * 128 + cidx) ^ fragSwz;
    uint4 au = *(uint4*)&sA[sidx];
    short8 ah = __builtin_bit_cast(short8, au);
    short8 al;
    if (!in_bf16) al = __builtin_bit_cast(short8, *(uint4*)&sA[64 * 128 + sidx]);
#pragma unroll
    for (int ct = 0; ct < 8; ++ct) {
      int widx = (ct * 4 + ks) * 64 + lane;
      short8 bh = __builtin_bit_cast(short8, wHi[widx]);
      short8 bl = __builtin_bit_cast(short8, wLo[widx]);
      if (!in_bf16) acc[ct] = __builtin_amdgcn_mfma_f32_16x16x32_bf16(al, bh, acc[ct], 0, 0, 0);
      acc[ct] = __builtin_amdgcn_mfma_f32_16x16x32_bf16(ah, bl, acc[ct], 0, 0, 0);
      acc[ct] = __builtin_amdgcn_mfma_f32_16x16x32_bf16(ah, bh, acc[ct], 0, 0, 0);
    }
  }

  float rs[4];
#pragma unroll
  for (int r = 0; r < 4; ++r) {
    int grow = row0 + rbase + ((lane >> 4) << 2) + r;
    rs[r] = rowscale ? ((grow < n) ? rowscale[grow] : 0.f) : 1.0f;
  }

  float hp0[4] = {0.f, 0.f, 0.f, 0.f};
  float hp1[4] = {0.f, 0.f, 0.f, 0.f};

#pragma unroll
  for (int ct = 0; ct < 8; ++ct) {
    int col = ct * 16 + (lane & 15);
    float bv = bias ? bias[col] : 0.f;
    float hw0 = 0.f, hw1 = 0.f;
    if (headOut) {
      hw0 = headW[col * 2 + 0];
      hw1 = headW[col * 2 + 1];
    }
#pragma unroll
    for (int r = 0; r < 4; ++r) {
      int rowL = rbase + ((lane >> 4) << 2) + r;
      float v = acc[ct][r] * rs[r] + bv;
      v = (v > 0.f) ? v : v * slope;
      if (outb) {
        int sidx = (rowL * 128 + col) ^ ((rowL & 7) << 3);
        sO[sidx] = (unsigned short)bf16_rtne(v);
      }
      if (headOut) {
        hp0[r] = fmaf(v, hw0, hp0[r]);
        hp1[r] = fmaf(v, hw1, hp1[r]);
      }
    }
  }

  if (headOut) {
    float hb0 = headB[0], hb1 = headB[1];
#pragma unroll
    for (int r = 0; r < 4; ++r) {
      float a = hp0[r], b = hp1[r];
#pragma unroll
      for (int off = 8; off; off >>= 1) {
        a += __shfl_xor(a, off);
        b += __shfl_xor(b, off);
      }
      if ((lane & 15) == 0) {
        int grow = row0 + rbase + ((lane >> 4) << 2) + r;
        if (grow < n) {
          float o0 = a + hb0, o1 = b + hb1;
          headOut[2 * (size_t)grow + 0] = (o0 > 0.f) ? o0 : 0.01f * o0;
          headOut[2 * (size_t)grow + 1] = (o1 > 0.f) ? o1 : 0.01f * o1;
        }
      }
    }
  }

  if (outb) {
    __syncthreads();
#pragma unroll
    for (int it = 0; it < 4; ++it) {
      int s = it * 64 + lane;
      int row = rbase + (s >> 4);
      int sin = s & 15;
      int sidx = row * 128 + ((sin * 8) ^ ((row & 7) << 3));
      uint4 v = *(uint4*)&sO[sidx];
      int grow = row0 + row;
      if (grow < n) *(uint4*)(outb + (size_t)grow * 64 + sin * 4) = v;
    }
  }
}

// ---------------- GCN aggregation: 4 rows per VMEM instr ----------------
// Wave = 1 node. Lane group q=lane>>4 handles edge e+q; lane p=lane&15 holds
// the p-th 16B chunk (8 bf16 features) of that edge's row. Group-reduce via
// shfl_xor(16/32) at the end. Output bf16 row; optional fused fprob.

__launch_bounds__(256)
__global__ void agg_kernel(const uint32* __restrict__ g, const int* __restrict__ row_beg,
                           const int* __restrict__ row_end, const int* __restrict__ cols,
                           const float* __restrict__ dinv, const float* __restrict__ bias,
                           uint32* __restrict__ out, int n, int relu,
                           const float* __restrict__ fpW, const float* __restrict__ fpB,
                           float* __restrict__ fpOut) {
  int lane = threadIdx.x & 63;
  int node = (blockIdx.x * blockDim.x + threadIdx.x) >> 6;
  if (node >= n) return;
  int grp = lane >> 4;
  int p = lane & 15;
  int beg = row_beg[node], end = row_end[node];
  const uint4* __restrict__ g4 = (const uint4*)g;  // row = 16 uint4

  float acc[8];
#pragma unroll
  for (int j = 0; j < 8; ++j) acc[j] = 0.f;

  int e = beg;
  // main: 8 edges per iteration (2 quad-loads in flight), no predication
  for (; e + 8 <= end; e += 8) {
    int c0 = cols[e + grp];
    int c1 = cols[e + 4 + grp];
    uint4 v0 = g4[(size_t)c0 * 16 + p];
    uint4 v1 = g4[(size_t)c1 * 16 + p];
    acc[0] += lo16f(v0.x); acc[1] += hi16f(v0.x);
    acc[2] += lo16f(v0.y); acc[3] += hi16f(v0.y);
    acc[4] += lo16f(v0.z); acc[5] += hi16f(v0.z);
    acc[6] += lo16f(v0.w); acc[7] += hi16f(v0.w);
    acc[0] += lo16f(v1.x); acc[1] += hi16f(v1.x);
    acc[2] += lo16f(v1.y); acc[3] += hi16f(v1.y);
    acc[4] += lo16f(v1.z); acc[5] += hi16f(v1.z);
    acc[6] += lo16f(v1.w); acc[7] += hi16f(v1.w);
  }
  // tail: predicated quads
  for (; e < end; e += 4) {
    int idx = e + grp;
    if (idx < end) {
      int c = cols[idx];
      uint4 v = g4[(size_t)c * 16 + p];
      acc[0] += lo16f(v.x); acc[1] += hi16f(v.x);
      acc[2] += lo16f(v.y); acc[3] += hi16f(v.y);
      acc[4] += lo16f(v.z); acc[5] += hi16f(v.z);
      acc[6] += lo16f(v.w); acc[7] += hi16f(v.w);
    }
  }

  // reduce across the 4 edge-groups
#pragma unroll
  for (int j = 0; j < 8; ++j) {
    acc[j] += __shfl_xor(acc[j], 16);
    acc[j] += __shfl_xor(acc[j], 32);
  }

  // self term (broadcast load across groups)
  {
    uint4 sv = g4[(size_t)node * 16 + p];
    acc[0] += lo16f(sv.x); acc[1] += hi16f(sv.x);
    acc[2] += lo16f(sv.y); acc[3] += hi16f(sv.y);
    acc[4] += lo16f(sv.z); acc[5] += hi16f(sv.z);
    acc[6] += lo16f(sv.w); acc[7] += hi16f(sv.w);
  }

  float di = dinv[node];
  const float4* b4 = (const float4*)bias;
  float4 bv0 = b4[2 * p], bv1 = b4[2 * p + 1];
  float o[8];
  o[0] = fmaf(di, acc[0], bv0.x); o[1] = fmaf(di, acc[1], bv0.y);
  o[2] = fmaf(di, acc[2], bv0.z); o[3] = fmaf(di, acc[3], bv0.w);
  o[4] = fmaf(di, acc[4], bv1.x); o[5] = fmaf(di, acc[5], bv1.y);
  o[6] = fmaf(di, acc[6], bv1.z); o[7] = fmaf(di, acc[7], bv1.w);
  if (relu) {
#pragma unroll
    for (int j = 0; j < 8; ++j) o[j] = fmaxf(o[j], 0.f);
  }

  if (fpOut) {
    float p0 = 0.f, p1 = 0.f;
#pragma unroll
    for (int j = 0; j < 8; ++j) {
      int col = p * 8 + j;
      p0 = fmaf(o[j], fpW[col * 2 + 0], p0);
      p1 = fmaf(o[j], fpW[col * 2 + 1], p1);
    }
#pragma unroll
    for (int off = 8; off; off >>= 1) {
      p0 += __shfl_xor(p0, off);
      p1 += __shfl_xor(p1, off);
    }
    if (lane == 0) {
      fpOut[2 * (size_t)node + 0] = p0 + fpB[0];
      fpOut[2 * (size_t)node + 1] = p1 + fpB[1];
    }
  }

  if (grp == 0) {
    uint4 pk;
    pk.x = bf16_rtne(o[0]) | (bf16_rtne(o[1]) << 16);
    pk.y = bf16_rtne(o[2]) | (bf16_rtne(o[3]) << 16);
    pk.z = bf16_rtne(o[4]) | (bf16_rtne(o[5]) << 16);
    pk.w = bf16_rtne(o[6]) | (bf16_rtne(o[7]) << 16);
    ((uint4*)out)[(size_t)node * 16 + p] = pk;
  }
}

// ---------------- y heads (both in one launch, bf16 Z) ----------------

__global__ void ydot2_kernel(const uint32* __restrict__ Z,
                             const int* __restrict__ idxA, const float* __restrict__ wA,
                             const float* __restrict__ bA, float* __restrict__ outA,
                             const int* __restrict__ idxB, const float* __restrict__ wB,
                             const float* __restrict__ bB, float* __restrict__ outB,
                             int T) {
  int lane = threadIdx.x & 63;
  int t = (blockIdx.x * blockDim.x + threadIdx.x) >> 6;
  if (t >= 2 * T) return;
  int isB = (t >= T);
  int ti = isB ? (t - T) : t;
  const int* idx = isB ? idxB : idxA;
  const float* w = isB ? wB : wA;
  const float* b = isB ? bB : bA;
  float* o = isB ? outB : outA;
  float2 wv = ((const float2*)w)[lane];
  int node = idx[ti];
  float zx, zy;
  unpack2(Z[(size_t)node * 64 + lane], zx, zy);
  float pp = zx * wv.x + zy * wv.y;
#pragma unroll
  for (int off = 32; off; off >>= 1) pp += __shfl_xor(pp, off);
  if (lane == 0) {
    float v = pp + b[0];
    o[ti] = (v > 0.f) ? v : 0.01f * v;
  }
}

// ---------------- launch ----------------

extern "C" void kernel_launch(void* const* d_in, const int* in_sizes, int n_in,
                              void* d_out, int out_size, void* d_ws, size_t ws_size,
                              hipStream_t stream) {
  const int N = in_sizes[0] / DIM;
  const int E = in_sizes[1] / 2;
  const int T = in_sizes[4];
  const int nb1 = (N + BINN - 1) >> BINSH;          // coarse bins (391)
  const int nA = (E + EPB - 1) / EPB;               // pass-A blocks (391)
  const int binCap = ((E / nb1 + 1024 + 15) / 16) * 16;  // per-bin cols capacity

  const float* x = (const float*)d_in[0];
  const int* ei = (const int*)d_in[1];
  const float* fx = (const float*)d_in[2];
  const int* fei = (const int*)d_in[3];
  const int* treat = (const int*)d_in[4];
  const int* control = (const int*)d_in[5];
  const float* W1 = (const float*)d_in[6];
  const float* b1 = (const float*)d_in[7];
  const float* W2 = (const float*)d_in[8];
  const float* b2 = (const float*)d_in[9];
  const float* Wy1 = (const float*)d_in[10];
  const float* by1 = (const float*)d_in[11];
  const float* Wy0 = (const float*)d_in[12];
  const float* by0 = (const float*)d_in[13];
  const float* Wb = (const float*)d_in[14];
  const float* bb = (const float*)d_in[15];
  const float* Wp1 = (const float*)d_in[16];
  const float* bp1 = (const float*)d_in[17];
  const float* Wp2 = (const float*)d_in[18];
  const float* bp2 = (const float*)d_in[19];

  float* out = (float*)d_out;

  // workspace layout (~95 MB)
  char* p = (char*)d_ws;
  float* bufZ = (float*)p;   p += (size_t)N * DIM * sizeof(float);          // bf16 Z1/Z2 (25.6 MB used) / CSR tmp
  uint32* bufG = (uint32*)p; p += (size_t)N * (DIM / 2) * sizeof(uint32);   // 25.6 MB (bf16 g rows)
  int* cols = (int*)p;       p += (size_t)nb1 * binCap * sizeof(int);       // ~14.4 MB
  int* dir = (int*)p;        p += (size_t)nA * (nb1 + 1) * sizeof(int);     // ~0.6 MB
  int* row_beg = (int*)p;    p += (size_t)(N + 16) * sizeof(int);
  int* row_end = (int*)p;    p += (size_t)(N + 16) * sizeof(int);
  float* dinv = (float*)p;   p += (size_t)(N + 16) * sizeof(float);
  uint4* w1Hi = (uint4*)p;   p += 2048 * sizeof(uint4);
  uint4* w1Lo = (uint4*)p;   p += 2048 * sizeof(uint4);
  uint4* w2Hi = (uint4*)p;   p += 2048 * sizeof(uint4);
  uint4* w2Lo = (uint4*)p;   p += 2048 * sizeof(uint4);
  uint4* wp1Hi = (uint4*)p;  p += 2048 * sizeof(uint4);
  uint4* wp1Lo = (uint4*)p;  p += 2048 * sizeof(uint4);
  uint32* tmp = (uint32*)bufZ;   // 12.8 MB staging aliases bufZ (free during CSR build)

  float* oy1 = out;
  float* oyc0 = out + T;
  float* oy0 = out + 2 * T;
  float* oyc1 = out + 3 * T;
  float* ofp = out + 4 * T;
  float* ofpf = out + 4 * T + 2 * N;
  float* otp = out + 4 * T + 4 * N;
  float* otpf = out + 4 * T + 6 * N;

  wsplit3_kernel<<<24, 256, 0, stream>>>(W1, w1Hi, w1Lo, W2, w2Hi, w2Lo, Wp1, wp1Hi, wp1Lo);

  auto run = [&](const float* X, const int* EI,
                 float* y_t, const float* Wt, const float* bt,
                 float* y_c, const float* Wc, const float* bc,
                 float* fp, float* tp) {
    const int* srcp = EI;
    const int* dstp = EI + E;
    // two-pass coalesced CSR build (zero global atomics)
    csr_sort_kernel<<<nA, 256, 0, stream>>>(srcp, dstp, E, nb1, tmp, dir);
    csr_build_kernel<<<nb1, 256, 0, stream>>>(tmp, dir, nA, nb1, N, binCap,
                                              row_beg, row_end, cols, dinv);
    // layer 1: g1 = (X@W1)*dinv (bf16); Z1 = relu(agg) stored bf16 in bufZ
    gemm_mfma_kernel<<<(N + 63) / 64, 256, 0, stream>>>(X, w1Hi, w1Lo, bufG, N, dinv,
                                                        nullptr, 1.0f, 0, nullptr, nullptr, nullptr);
    agg_kernel<<<(N + 3) / 4, 256, 0, stream>>>(bufG, row_beg, row_end, cols, dinv, b1,
                                                (uint32*)bufZ, N, 1, nullptr, nullptr, nullptr);
    // layer 2: bf16-exact input (2 MFMA); Z2 bf16 + fused fprob (fp32 in-reg)
    gemm_mfma_kernel<<<(N + 63) / 64, 256, 0, stream>>>(bufZ, w2Hi, w2Lo, bufG, N, dinv,
                                                        nullptr, 1.0f, 1, nullptr, nullptr, nullptr);
    agg_kernel<<<(N + 3) / 4, 256, 0, stream>>>(bufG, row_beg, row_end, cols, dinv, b2,
                                                (uint32*)bufZ, N, 0, Wb, bb, fp);
    // tprob: Wp1 gemm (bf16 Z2 input) with fused stage-2 head, no intermediate write
    gemm_mfma_kernel<<<(N + 63) / 64, 256, 0, stream>>>(bufZ, wp1Hi, wp1Lo, nullptr, N, nullptr,
                                                        bp1, 0.01f, 1, Wp2, bp2, tp);
    // y heads (both in one launch)
    ydot2_kernel<<<(2 * T + 3) / 4, 256, 0, stream>>>((const uint32*)bufZ,
                                                      treat, Wt, bt, y_t,
                                                      control, Wc, bc, y_c, T);
  };

  run(x, ei, oy1, Wy1, by1, oy0, Wy0, by0, ofp, otp);
  run(fx, fei, oyc0, Wy0, by0, oyc1, Wy1, by1, ofpf, otpf);
}